// Round 1
// baseline (1028.617 us; speedup 1.0000x reference)
//
#include <hip/hip_runtime.h>

// CTC loss forward (alpha recursion), matching keras ctc_batch_cost reference.
// Shapes fixed by the problem: B=128, T=1024, V=512, L=128.
constexpr int Bc = 128;
constexpr int Tc = 1024;
constexpr int Vc = 512;
constexpr int Lc = 128;
constexpr int Sc = 2 * Lc + 1;     // 257 extended states
constexpr int BLANK = Vc - 1;      // 511
constexpr float NEGF = -1e30f;
constexpr float EPSF = 1e-7f;
constexpr int PF = 8;              // prefetch ring depth (covers ~900cy HBM latency)

__launch_bounds__(256, 1)
__global__ void ctc_fwd_kernel(const int* __restrict__ labels,      // [B,L]
                               const int* __restrict__ label_len,   // [B,1]
                               const float* __restrict__ probs,     // [B,T,V]
                               const int* __restrict__ input_len,   // [B,1]
                               float* __restrict__ out)             // [B,1]
{
    const int b   = blockIdx.x;
    const int tid = threadIdx.x;   // state s = tid; tid==0 also handles s=256

    __shared__ float buf[2][Sc + 1];   // double-buffered alpha

    // Fixed emission column for this state; can_skip for odd states s>=3.
    int col;
    bool can_skip = false;
    if (tid & 1) {
        const int li = tid >> 1;              // (s-1)/2
        col = labels[b * Lc + li];
        if (tid >= 3) {
            const int prev = labels[b * Lc + li - 1];
            can_skip = (col != prev);
        }
    } else {
        col = BLANK;
    }

    const int len = input_len[b];

    // alpha0: state 0 = 0.0, rest = NEG
    float a = (tid == 0) ? 0.0f : NEGF;
    float a_last = NEGF;                       // state 256 (thread 0 only)
    buf[0][tid] = a;
    if (tid == 0) buf[0][Sc - 1] = NEGF;

    // Prefetch ring: probs[b, t, col] for t = 0..PF-1
    const float* __restrict__ pcol = probs + (size_t)b * Tc * Vc + col;
    float pf[PF];
#pragma unroll
    for (int j = 0; j < PF; ++j)
        pf[j] = pcol[(size_t)j * Vc];

    __syncthreads();

    int cur = 0;
    for (int t0 = 0; t0 < Tc; t0 += PF) {
#pragma unroll
        for (int j = 0; j < PF; ++j) {
            const int t = t0 + j;
            const float p = pf[j];
            const int tn = t + PF;
            if (tn < Tc) pf[j] = pcol[(size_t)tn * Vc];   // refill ring

            const float lp = __logf(p + EPSF);

            // neighbors at time t (from buf[cur])
            const int im1 = (tid >= 1) ? tid - 1 : 0;
            const int im2 = (tid >= 2) ? tid - 2 : 0;
            float am1 = buf[cur][im1];
            float am2 = buf[cur][im2];
            if (tid < 1)   am1 = NEGF;
            if (!can_skip) am2 = NEGF;

            // 3-way logaddexp (NEG terms vanish via exp underflow)
            const float m   = fmaxf(fmaxf(a, am1), am2);
            const float sum = __expf(a - m) + __expf(am1 - m) + __expf(am2 - m);
            float anew = m + __logf(sum) + lp;
            if (t >= len) anew = a;            // freeze past input length

            float a256new = 0.0f;
            if (tid == 0) {                    // state 256: 2-way with state 255
                const float am1l = buf[cur][Sc - 2];
                const float m2   = fmaxf(a_last, am1l);
                const float s2   = __expf(a_last - m2) + __expf(am1l - m2);
                a256new = m2 + __logf(s2) + lp;   // same lp (blank)
                if (t >= len) a256new = a_last;
            }

            const int nxt = cur ^ 1;
            buf[nxt][tid] = anew;
            a = anew;
            if (tid == 0) { buf[nxt][Sc - 1] = a256new; a_last = a256new; }
            __syncthreads();
            cur = nxt;
        }
    }

    if (tid == 0) {
        const int lab = label_len[b];
        const float x = buf[cur][2 * lab];
        const float y = buf[cur][2 * lab - 1];
        const float m = fmaxf(x, y);
        const float loss = -(m + __logf(__expf(x - m) + __expf(y - m)));
        out[b] = loss;
    }
}

extern "C" void kernel_launch(void* const* d_in, const int* in_sizes, int n_in,
                              void* d_out, int out_size, void* d_ws, size_t ws_size,
                              hipStream_t stream) {
    const int*   labels    = (const int*)d_in[0];   // true_labels   [B,L] int32
    const int*   label_len = (const int*)d_in[1];   // true_lengths  [B,1] int32
    const float* probs     = (const float*)d_in[2]; // predicted_labels [B,T,V] f32
    const int*   input_len = (const int*)d_in[3];   // predicted_lengths [B,1] int32
    float*       out       = (float*)d_out;         // [B,1] f32

    const int B = in_sizes[1];                      // 128
    ctc_fwd_kernel<<<B, 256, 0, stream>>>(labels, label_len, probs, input_len, out);
}

// Round 2
// 738.535 us; speedup vs baseline: 1.3928x; 1.3928x over previous
//
#include <hip/hip_runtime.h>

// CTC loss forward, single wave per batch element: states in registers,
// neighbor exchange via one __shfl_up per step, NO barriers in the T-loop
// (barriers force s_waitcnt vmcnt(0) on gfx950 and defeat prefetching).
// Shapes fixed: B=128, T=1024, V=512, L=128, S=257.
constexpr int Tc = 1024;
constexpr int Vc = 512;
constexpr int Lc = 128;
constexpr int Sc = 2 * Lc + 1;     // 257
constexpr int BLANK = Vc - 1;      // 511
constexpr float NEGF = -1e30f;
constexpr float EPSF = 1e-7f;
constexpr int PF = 16;             // prefetch ring depth (3 loads/step -> 48 in flight)

__device__ __forceinline__ float lae2(float x, float y) {
    float m = fmaxf(x, y);
    return m + __logf(__expf(x - m) + __expf(y - m));
}
__device__ __forceinline__ float lae3(float x, float y, float z) {
    float m = fmaxf(fmaxf(x, y), z);
    return m + __logf(__expf(x - m) + __expf(y - m) + __expf(z - m));
}

__launch_bounds__(64, 1)
__global__ void ctc_fwd_wave(const int* __restrict__ labels,      // [B,L]
                             const int* __restrict__ label_len,   // [B,1]
                             const float* __restrict__ probs,     // [B,T,V]
                             const int* __restrict__ input_len,   // [B,1]
                             float* __restrict__ out)             // [B,1]
{
    const int b    = blockIdx.x;
    const int lane = threadIdx.x;          // lane L owns states 4L..4L+3; lane 63 also 256

    __shared__ float sa[Sc];

    // Labels for this lane's odd states: s=4L+1 -> label 2L, s=4L+3 -> label 2L+1
    const int lbase = b * Lc;
    const int l0  = labels[lbase + 2 * lane];
    const int l1  = labels[lbase + 2 * lane + 1];
    const int lm1 = (lane > 0) ? labels[lbase + 2 * lane - 1] : 0;
    const bool cs1 = (lane > 0) && (l0 != lm1);  // skip into state 4L+1 (s>=3 iff L>=1)
    const bool cs3 = (l1 != l0);                 // skip into state 4L+3 (s>=3 always)
    const int len = input_len[b];

    const float* __restrict__ base = probs + (size_t)b * Tc * Vc;
    const float* __restrict__ pB = base + BLANK;
    const float* __restrict__ p1 = base + l0;
    const float* __restrict__ p2 = base + l1;

    // Prefetch ring
    float rb[PF], r1[PF], r2[PF];
#pragma unroll
    for (int j = 0; j < PF; ++j) {
        const size_t o = (size_t)j * Vc;
        rb[j] = pB[o]; r1[j] = p1[o]; r2[j] = p2[o];
    }

    // alpha registers (time t-1 values)
    float a0 = (lane == 0) ? 0.0f : NEGF;   // state 4L
    float a1 = NEGF;                        // state 4L+1
    float a2 = NEGF;                        // state 4L+2
    float a3 = NEGF;                        // state 4L+3
    float a4 = NEGF;                        // state 256 (valid on lane 63)

    auto step = [&](int t, int j, bool refill) {
        const float lpb = __logf(rb[j] + EPSF);
        const float lp1 = __logf(r1[j] + EPSF);
        const float lp2 = __logf(r2[j] + EPSF);
        if (refill) {
            const size_t o = (size_t)(t + PF) * Vc;
            rb[j] = pB[o]; r1[j] = p1[o]; r2[j] = p2[o];
        }
        // prev lane's old state 4L-1 (only cross-lane value needed)
        float up3 = __shfl_up(a3, 1);
        if (lane == 0) up3 = NEGF;

        float n0 = lae2(a0, up3) + lpb;                        // even: no skip
        float n1 = lae3(a1, a0, cs1 ? up3 : NEGF) + lp1;       // odd
        float n2 = lae2(a2, a1) + lpb;                         // even: no skip
        float n3 = lae3(a3, a2, cs3 ? a1 : NEGF) + lp2;        // odd
        float n4 = lae2(a4, a3) + lpb;                         // state 256 (blank)

        const bool live = (t < len);
        a0 = live ? n0 : a0;
        a1 = live ? n1 : a1;
        a2 = live ? n2 : a2;
        a3 = live ? n3 : a3;
        a4 = live ? n4 : a4;
    };

    for (int t0 = 0; t0 < Tc - PF; t0 += PF) {
#pragma unroll
        for (int j = 0; j < PF; ++j) step(t0 + j, j, true);
    }
#pragma unroll
    for (int j = 0; j < PF; ++j) step(Tc - PF + j, j, false);

    // Gather final alphas and emit loss
    sa[4 * lane + 0] = a0;
    sa[4 * lane + 1] = a1;
    sa[4 * lane + 2] = a2;
    sa[4 * lane + 3] = a3;
    if (lane == 63) sa[256] = a4;
    __syncthreads();
    if (lane == 0) {
        const int lab = label_len[b];
        const float x = sa[2 * lab];
        const float y = sa[2 * lab - 1];
        out[b] = -lae2(x, y);
    }
}

extern "C" void kernel_launch(void* const* d_in, const int* in_sizes, int n_in,
                              void* d_out, int out_size, void* d_ws, size_t ws_size,
                              hipStream_t stream) {
    const int*   labels    = (const int*)d_in[0];   // true_labels   [B,L]
    const int*   label_len = (const int*)d_in[1];   // true_lengths  [B,1]
    const float* probs     = (const float*)d_in[2]; // predicted_labels [B,T,V]
    const int*   input_len = (const int*)d_in[3];   // predicted_lengths [B,1]
    float*       out       = (float*)d_out;         // [B,1]

    const int B = in_sizes[1];
    ctc_fwd_wave<<<B, 64, 0, stream>>>(labels, label_len, probs, input_len, out);
}